// Round 4
// baseline (376.474 us; speedup 1.0000x reference)
//
#include <hip/hip_runtime.h>

// RoIAlign: features (B=8, C=512, H=60, W=80) fp32, rois (N=1024,7) fp32
// out (N, C, 7, 7) fp32.
// R4: kill the scattered gather (R3 was L1-transaction bound: 103M scattered
// dword gathers, ~16-30 lines per wave-load, 97us at only 15% VALU / 20% HBM).
// Block = (roi slot, bin row i, 128-ch slice cs). Stage rows hi,hi+1 x cols
// [wi0&~3, wi6+1] (span <= 36: roi_w <= 239px * 0.125 = 29.875) for 128 ch
// into LDS via coalesced float4 loads; taps become ds_read2_b32 pairs.
// LDS channel stride 76 floats (== 12 mod 32 banks, step 12 has period 8)
// makes the b128 staging writes bank-conflict-free. XCD<->batch perm kept.

constexpr int   Bb = 8;
constexpr int   Cc = 512;
constexpr int   Hh = 60;
constexpr int   Ww = 80;
constexpr int   HW = Hh * Ww;
constexpr int   Nn = 1024;
constexpr int   AH = 7;
constexpr int   AW = 7;
constexpr int   NB = AH * AW;            // 49
constexpr int   CSPLIT = 4;
constexpr int   CPB = Cc / CSPLIT;       // 128 channels per block
constexpr int   TW = 36;                 // staged cols per row (max span 35)
constexpr int   CH_STRIDE = 2 * TW + 4;  // 76 floats: 12 mod 32 banks
constexpr int   QUOTA = Nn / Bb;         // 128
constexpr float SCALE = 0.125f;

// ---- prepass: slot j gets a ROI of batch j%8 when possible (XCD affinity)
__global__ __launch_bounds__(1024) void roi_perm_kernel(
    const float* __restrict__ rois, int* __restrict__ perm)
{
    __shared__ int cnt[Bb];
    __shared__ int ovf[Nn];
    __shared__ int novf;
    __shared__ int ntake;
    const int tid = threadIdx.x;
    if (tid < Bb) cnt[tid] = 0;
    if (tid == 0) { novf = 0; ntake = 0; }
    perm[tid] = -1;
    __syncthreads();
    {
        const int b = (int)rois[tid * 7];
        const int pos = atomicAdd(&cnt[b], 1);
        if (pos < QUOTA) perm[b + Bb * pos] = tid;
        else             ovf[atomicAdd(&novf, 1)] = tid;
    }
    __syncthreads();
    if (perm[tid] < 0) perm[tid] = ovf[atomicAdd(&ntake, 1)];
}

__global__ __launch_bounds__(256) void roialign_kernel(
    const float* __restrict__ feats,
    const float* __restrict__ rois,
    const int* __restrict__ perm,
    float* __restrict__ out)
{
    __shared__ float s_f[CPB * CH_STRIDE];  // [ch][r*TW + x], 38.9 KB
    __shared__ int   s_wx[AW];              // wi(j) - col0
    __shared__ float s_wr[AW];
    __shared__ float s_mk[AW];              // valid_h && valid_w(j)
    __shared__ float s_hr;

    const int slot = blockIdx.x & (Nn - 1);
    const int p    = blockIdx.x >> 10;      // 0..27, = cs*7 + i
    const int i    = p % AH;
    const int cs   = p / AH;
    const int tid  = threadIdx.x;

    const int n = perm[slot];
    const float* rp = rois + n * 7;

    // ---- per-ROI params, computed redundantly in every thread (cheap VALU)
    const float x1 = rp[2] * SCALE, y1 = rp[3] * SCALE;
    const float x2 = rp[4] * SCALE, y2 = rp[5] * SCALE;
    const float bin_h = fmaxf(y2 - y1, 0.0f) * (1.0f / (AH - 1));
    const float bin_w = fmaxf(x2 - x1, 0.0f) * (1.0f / (AW - 1));
    const float h  = y1 + (float)i * bin_h;
    const float hs = fminf(floorf(h), (float)(Hh - 2));
    const int   hi = (int)fminf(fmaxf(hs, 0.0f), (float)(Hh - 2));
    const bool  vh = (h >= 0.0f) && (h < (float)Hh);

    int col0, colEnd;
    {
        // wi(j) is nondecreasing in j (bin_w >= 0)
        const float w0f = x1;
        const float w6f = x1 + 6.0f * bin_w;
        const int wi0 = (int)fminf(fmaxf(fminf(floorf(w0f), (float)(Ww - 2)), 0.0f), (float)(Ww - 2));
        const int wi6 = (int)fminf(fmaxf(fminf(floorf(w6f), (float)(Ww - 2)), 0.0f), (float)(Ww - 2));
        col0   = wi0 & ~3;
        colEnd = wi6 + 2;                 // exclusive; span <= 35 <= TW
    }
    const int ncol4 = (colEnd - col0 + 3) >> 2;   // <= 9

    if (tid < AW) {
        const float w  = x1 + (float)tid * bin_w;
        const float wsf = fminf(floorf(w), (float)(Ww - 2));
        const int   wi = (int)fminf(fmaxf(wsf, 0.0f), (float)(Ww - 2));
        const bool  vw = (w >= 0.0f) && (w < (float)Ww);
        s_wx[tid] = wi - col0;
        s_wr[tid] = w - wsf;
        s_mk[tid] = (vh && vw) ? 1.0f : 0.0f;
        if (tid == 0) s_hr = h - hs;
    }

    // ---- stage: thread t -> channel t>>1, row t&1; float4s along cols
    const int fbase = (int)rp[0] * (Cc * HW) + cs * (CPB * HW);
    {
        const int ch = tid >> 1;
        const int r  = tid & 1;
        const float* src = feats + fbase + ch * HW + (hi + r) * Ww;
        float* dst = &s_f[ch * CH_STRIDE + r * TW];
        for (int c4 = 0; c4 < ncol4; ++c4) {
            const int cc = min(col0 + 4 * c4, Ww - 4);  // clamp: never read past row
            const float4 v = *(const float4*)(src + cc);
            *(float4*)(dst + (cc - col0)) = v;
        }
    }
    __syncthreads();

    // ---- compute: 128 ch x 7 j = 896 outputs, 4 LDS taps each
    const float hr = s_hr;
    float* ob = out + (size_t)n * (Cc * NB) + cs * (CPB * NB) + i * AW;
    for (int tt = tid; tt < CPB * AW; tt += 256) {
        const int ch = tt / AW;            // magic-mul by 7
        const int j  = tt - ch * AW;
        const float wr  = s_wr[j];
        const float msk = s_mk[j];
        const float* base = &s_f[ch * CH_STRIDE + s_wx[j]];
        const float v00 = base[0];
        const float v01 = base[1];
        const float v10 = base[TW];
        const float v11 = base[TW + 1];
        const float top = v00 + (v01 - v00) * wr;
        const float bot = v10 + (v11 - v10) * wr;
        __builtin_nontemporal_store((top + (bot - top) * hr) * msk,
                                    &ob[ch * NB + j]);
    }
}

extern "C" void kernel_launch(void* const* d_in, const int* in_sizes, int n_in,
                              void* d_out, int out_size, void* d_ws, size_t ws_size,
                              hipStream_t stream) {
    const float* feats = (const float*)d_in[0];
    const float* rois  = (const float*)d_in[1];
    float* out = (float*)d_out;
    int* perm = (int*)d_ws;              // 1024 ints
    roi_perm_kernel<<<1, 1024, 0, stream>>>(rois, perm);
    roialign_kernel<<<Nn * AH * CSPLIT, 256, 0, stream>>>(feats, rois, perm, out);
}

// Round 5
// 217.824 us; speedup vs baseline: 1.7283x; 1.7283x over previous
//
#include <hip/hip_runtime.h>

// RoIAlign: features (B=8, C=512, H=60, W=80) fp32, rois (N=1024,7) fp32
// out (N, C, 7, 7) fp32.
// R5 = R3 (97us, L1-gather-transaction bound: ~40M line-transactions from
// 1.6M scattered wave-loads) + paired horizontal taps: (v00,v01) and
// (v10,v11) each loaded as one <2 x float, align 4> -> global_load_dwordx2,
// halving gather instructions and thus L1 transactions. R4's LDS-staging
// variant regressed (write pattern broke 49-float channel runs -> 227 MB
// RMW writes); reverted. XCD<->batch perm (R3) kept: FETCH 500->50 MB.

constexpr int   Bb = 8;
constexpr int   Cc = 512;
constexpr int   Hh = 60;
constexpr int   Ww = 80;
constexpr int   HW = Hh * Ww;
constexpr int   Nn = 1024;
constexpr int   AH = 7;
constexpr int   AW = 7;
constexpr int   NB = AH * AW;            // 49 bins
constexpr int   CSPLIT = 4;              // channel phases
constexpr int   CPB = Cc / CSPLIT;       // 128 channels per block
constexpr int   OUT_PER_BLK = CPB * NB;  // 6272
constexpr int   QUOTA = Nn / Bb;         // 128
constexpr float SCALE = 0.125f;

// 8-byte vector load with only 4-byte alignment guarantee: backend emits one
// global_load_dwordx2 (unaligned global access OK on gfx950); if it ever
// splits, we get exactly the R3 code -> correctness identical either way.
typedef float f2v __attribute__((ext_vector_type(2)));
typedef f2v unaligned_f2v __attribute__((aligned(4)));

// ---- prepass: slot j gets a ROI of batch j%8 when possible (XCD affinity)
__global__ __launch_bounds__(1024) void roi_perm_kernel(
    const float* __restrict__ rois, int* __restrict__ perm)
{
    __shared__ int cnt[Bb];
    __shared__ int ovf[Nn];
    __shared__ int novf;
    __shared__ int ntake;
    const int tid = threadIdx.x;
    if (tid < Bb) cnt[tid] = 0;
    if (tid == 0) { novf = 0; ntake = 0; }
    perm[tid] = -1;
    __syncthreads();
    {
        const int b = (int)rois[tid * 7];
        const int pos = atomicAdd(&cnt[b], 1);
        if (pos < QUOTA) perm[b + Bb * pos] = tid;
        else             ovf[atomicAdd(&novf, 1)] = tid;
    }
    __syncthreads();
    if (perm[tid] < 0) perm[tid] = ovf[atomicAdd(&ntake, 1)];
}

__global__ __launch_bounds__(256) void roialign_kernel(
    const float* __restrict__ feats,
    const float* __restrict__ rois,
    const int* __restrict__ perm,
    float* __restrict__ out)
{
    __shared__ int4 s_par[NB];   // {hi*W+wi, hr, wr, msk} bit-packed
    __shared__ int  s_fbase;

    const int slot = blockIdx.x & (Nn - 1);
    const int cs   = blockIdx.x >> 10;        // 0..CSPLIT-1
    const int n    = perm[slot];
    const int tid  = threadIdx.x;
    const float* rp = rois + n * 7;

    if (tid < NB) {
        const float x1 = rp[2] * SCALE, y1 = rp[3] * SCALE;
        const float x2 = rp[4] * SCALE, y2 = rp[5] * SCALE;
        const float bin_h = fmaxf(y2 - y1, 0.0f) * (1.0f / (AH - 1));
        const float bin_w = fmaxf(x2 - x1, 0.0f) * (1.0f / (AW - 1));
        const int i = tid / AW;
        const int j = tid - i * AW;
        const float h = y1 + (float)i * bin_h;
        const float w = x1 + (float)j * bin_w;
        // reference: hstart = min(floor(h), H-2); hr = h - hstart (may be >1)
        const float hs = fminf(floorf(h), (float)(Hh - 2));
        const float ws = fminf(floorf(w), (float)(Ww - 2));
        const int hi = (int)fminf(fmaxf(hs, 0.0f), (float)(Hh - 2));
        const int wi = (int)fminf(fmaxf(ws, 0.0f), (float)(Ww - 2));
        const bool valid = (h >= 0.0f) && (h < (float)Hh) &&
                           (w >= 0.0f) && (w < (float)Ww);
        int4 pr;
        pr.x = hi * Ww + wi;
        pr.y = __float_as_int(h - hs);
        pr.z = __float_as_int(w - ws);
        pr.w = __float_as_int(valid ? 1.0f : 0.0f);
        s_par[tid] = pr;
        if (tid == 0) s_fbase = (int)rp[0] * (Cc * HW);
    }
    __syncthreads();

    const float* fb = feats + s_fbase + cs * (CPB * HW);
    float* ob = out + (size_t)n * (Cc * NB) + cs * OUT_PER_BLK;

    #pragma unroll 4
    for (int k = tid; k < OUT_PER_BLK; k += 256) {
        const int c  = k / NB;           // magic-mul div by 49
        const int rr = k - c * NB;
        const int4 pr = s_par[rr];
        const float hr  = __int_as_float(pr.y);
        const float wr  = __int_as_float(pr.z);
        const float msk = __int_as_float(pr.w);
        const float* p = fb + c * HW + pr.x;
        const f2v t01 = *(const unaligned_f2v*)(p);        // v00, v01
        const f2v b01 = *(const unaligned_f2v*)(p + Ww);   // v10, v11
        const float top = t01.x + (t01.y - t01.x) * wr;
        const float bot = b01.x + (b01.y - b01.x) * wr;
        __builtin_nontemporal_store((top + (bot - top) * hr) * msk, &ob[k]);
    }
}

extern "C" void kernel_launch(void* const* d_in, const int* in_sizes, int n_in,
                              void* d_out, int out_size, void* d_ws, size_t ws_size,
                              hipStream_t stream) {
    const float* feats = (const float*)d_in[0];
    const float* rois  = (const float*)d_in[1];
    float* out = (float*)d_out;
    int* perm = (int*)d_ws;              // 1024 ints
    roi_perm_kernel<<<1, 1024, 0, stream>>>(rois, perm);
    roialign_kernel<<<Nn * CSPLIT, 256, 0, stream>>>(feats, rois, perm, out);
}